// Round 2
// baseline (108.169 us; speedup 1.0000x reference)
//
#include <hip/hip_runtime.h>
#include <math.h>

#define Bc 4
#define Cc 64
#define Hh 96
#define Ww 96
#define Oo 128
#define HW 9216          // Hh*Ww
#define PT 32            // positions per block
#define NPB 288          // 32-pos tiles per image
#define RR 7             // region rows  (ho-3 .. ho+3)
#define RC 38            // region cols  (wo0-3 .. wo0+34)
#define RS 72            // shorts per position record (144 B: 16B-aligned, 36 banks)

typedef __attribute__((ext_vector_type(8))) short bf16x8;
typedef __attribute__((ext_vector_type(4))) float f32x4;
typedef __attribute__((ext_vector_type(4))) unsigned int u32x4;

// low/high bf16 of a packed u32 as exact f32 (1 VALU op each)
__device__ inline float bf_lo(unsigned u) {
    return __builtin_bit_cast(float, u << 16);
}
__device__ inline float bf_hi(unsigned u) {
    return __builtin_bit_cast(float, u & 0xFFFF0000u);
}
// HW RNE pack of two f32 -> 2x bf16. Guide-verified recipe (T12/m240):
// src0 -> low short. NOTE: every bf16 producer in this file pairs along the
// channel (contraction) axis, so even a src-half swap would permute k
// identically on A and B of every MFMA -> output invariant by construction.
__device__ inline unsigned cvt_pk_bf16(float lo, float hi) {
    unsigned r;
    asm("v_cvt_pk_bf16_f32 %0, %1, %2" : "=v"(r) : "v"(lo), "v"(hi));
    return r;
}

// ---------------------------------------------------------------------------
// k_pre: (blocks 0..179) pack weights into MFMA fragment layouts, one channel
//        PAIR per thread via v_cvt_pk_bf16_f32;
//        (blocks 180..323) transpose x -> channels-last bf16 xT[b][h][w][c].
// ---------------------------------------------------------------------------
__global__ __launch_bounds__(256) void k_pre(
    const float* __restrict__ dw, const float* __restrict__ ow,
    const float* __restrict__ mw, const float* __restrict__ x,
    unsigned short* __restrict__ wTmF, unsigned short* __restrict__ w27F,
    unsigned short* __restrict__ xT)
{
    const int bid = blockIdx.x;
    const int t = threadIdx.x;
    if (bid < 180) {
        int i2 = (bid * 256 + t) * 2;            // even element index
        if (i2 < 9 * 8 * 2 * 512) {
            int j = i2 & 7;                      // even: pair (j, j+1) -> (c, c+1)
            int l = (i2 >> 3) & 63, fb = i2 >> 9;
            int s = fb & 1, m = (fb >> 1) & 7, k = fb >> 4;
            int oc = m * 16 + (l & 15);
            int c = s * 32 + (l >> 4) * 8 + j;
            float f0 = dw[(oc * 64 + c) * 9 + k];
            float f1 = dw[(oc * 64 + c + 1) * 9 + k];
            *(unsigned*)(wTmF + i2) = cvt_pk_bf16(f0, f1);
        } else {
            int jj = i2 - 9 * 8 * 2 * 512;
            if (jj < 9 * 2 * 2 * 512) {
                int j = jj & 7, l = (jj >> 3) & 63, fb2 = jj >> 9;
                int nt = fb2 & 1, s = (fb2 >> 1) & 1, k = fb2 >> 2;
                int ch = nt * 16 + (l & 15);
                int c = s * 32 + (l >> 4) * 8 + j;
                float f0 = 0.f, f1 = 0.f;
                if (ch < 18) {
                    f0 = ow[(ch * 64 + c) * 9 + k];
                    f1 = ow[(ch * 64 + c + 1) * 9 + k];
                } else if (ch < 27) {
                    f0 = mw[((ch - 18) * 64 + c) * 9 + k];
                    f1 = mw[((ch - 18) * 64 + c + 1) * 9 + k];
                }
                *(unsigned*)(w27F + jj) = cvt_pk_bf16(f0, f1);
            }
        }
    } else {
        int gp = (bid - 180) * 256 + t;          // 0..36863, one position each
        int b = gp / HW;
        int p = gp - b * HW;
        const float* xb = x + (size_t)b * Cc * HW + p;
        unsigned short* op = xT + (size_t)gp * 64;
#pragma unroll
        for (int q = 0; q < 8; ++q) {
            union { bf16x8 v8; unsigned u[4]; } u;
#pragma unroll
            for (int c = 0; c < 8; c += 2) {
                float f0 = xb[(size_t)(q * 8 + c) * HW];
                float f1 = xb[(size_t)(q * 8 + c + 1) * HW];
                u.u[c >> 1] = cvt_pk_bf16(f0, f1);   // 1 instr / 2 elements
            }
            *(bf16x8*)(op + q * 8) = u.v8;
        }
    }
}

// ---------------------------------------------------------------------------
// sample+GEMM over taps [K0,K1): corners come from the LDS region (fast path,
// wave-uniform ballot) with exact per-lane global fallback for tagged indices.
// Blend: scalar mul/fma (round-0-identical), HW cvt_pk_bf16 pack.
// ---------------------------------------------------------------------------
template <int K0, int K1>
__device__ __forceinline__ void sample_gemm(
    const short (&reg)[RR * RC * RS],
    const unsigned short* __restrict__ xTb,
    const unsigned short* __restrict__ wb,
    const float (&pw)[9][4][PT], const int (&pi)[9][4][PT],
    int pos_l, int cq, f32x4 (&acc)[8])
{
#pragma unroll
    for (int kk = K0; kk < K1; ++kk) {
        const float w0 = pw[kk][0][pos_l], w1 = pw[kk][1][pos_l];
        const float w2 = pw[kk][2][pos_l], w3 = pw[kk][3][pos_l];
        const int i0 = pi[kk][0][pos_l], i1 = pi[kk][1][pos_l];
        const int i2 = pi[kk][2][pos_l], i3 = pi[kk][3][pos_l];
        const unsigned long long anybad = __ballot((i0 | i1 | i2 | i3) < 0);

#pragma unroll
        for (int s = 0; s < 2; ++s) {
            const int so = s * 32 + cq;
            bf16x8 c0, c1, c2, c3;
            if (anybad == 0) {                       // wave-uniform fast path
                c0 = *(const bf16x8*)(&reg[i0 + so]);
                c1 = *(const bf16x8*)(&reg[i1 + so]);
                c2 = *(const bf16x8*)(&reg[i2 + so]);
                c3 = *(const bf16x8*)(&reg[i3 + so]);
            } else {                                 // rare exact fallback
                c0 = (i0 < 0) ? *(const bf16x8*)(xTb + (i0 & 0x7FFFFFFF) + so)
                              : *(const bf16x8*)(&reg[i0 + so]);
                c1 = (i1 < 0) ? *(const bf16x8*)(xTb + (i1 & 0x7FFFFFFF) + so)
                              : *(const bf16x8*)(&reg[i1 + so]);
                c2 = (i2 < 0) ? *(const bf16x8*)(xTb + (i2 & 0x7FFFFFFF) + so)
                              : *(const bf16x8*)(&reg[i2 + so]);
                c3 = (i3 < 0) ? *(const bf16x8*)(xTb + (i3 & 0x7FFFFFFF) + so)
                              : *(const bf16x8*)(&reg[i3 + so]);
            }
            const u32x4 U0 = __builtin_bit_cast(u32x4, c0);
            const u32x4 U1 = __builtin_bit_cast(u32x4, c1);
            const u32x4 U2 = __builtin_bit_cast(u32x4, c2);
            const u32x4 U3 = __builtin_bit_cast(u32x4, c3);
            union { bf16x8 v8; unsigned u[4]; } B;
#pragma unroll
            for (int p = 0; p < 4; ++p) {            // element pair (2p, 2p+1)
                float r0 = w0 * bf_lo(U0[p]) + w1 * bf_lo(U1[p])
                         + w2 * bf_lo(U2[p]) + w3 * bf_lo(U3[p]);
                float r1 = w0 * bf_hi(U0[p]) + w1 * bf_hi(U1[p])
                         + w2 * bf_hi(U2[p]) + w3 * bf_hi(U3[p]);
                B.u[p] = cvt_pk_bf16(r0, r1);
            }
#pragma unroll
            for (int m = 0; m < 8; ++m) {
                bf16x8 A = *(const bf16x8*)(wb + (size_t)((kk * 16 + m * 2 + s) << 9));
                acc[m] = __builtin_amdgcn_mfma_f32_16x16x32_bf16(A, B.v8, acc[m], 0, 0, 0);
            }
        }
    }
}

// ---------------------------------------------------------------------------
// k_fused: halo region (7x38, LDS) -> offset/mask conv (MFMA) -> sigmoid ->
// bilinear params (region-relative indices) -> tap-split LDS sampling + MFMA
// GEMM -> LDS merge -> store.
// ---------------------------------------------------------------------------
__global__ __launch_bounds__(256, 3) void k_fused(
    const unsigned short* __restrict__ xT, const float* __restrict__ ob,
    const float* __restrict__ mb, const unsigned short* __restrict__ w27F,
    const unsigned short* __restrict__ wTmF, float* __restrict__ out)
{
    __shared__ union RU {
        short reg[RR * RC * RS];                   // 38304 B, phases 0-3
        float mg[8 * 520];                         // 16640 B, merge epilogue
    } R;
    __shared__ float s_pw[9][4][PT];               // 4608 B
    __shared__ int   s_pi[9][4][PT];               // 4608 B
    __shared__ float offm_s[27 * 33];              // 3564 B

    const int t = threadIdx.x;
    const int lid = (blockIdx.x & 7) * 144 + (blockIdx.x >> 3);
    const int bb = lid / NPB;
    const int tile = lid - bb * NPB;
    const int ho = tile / 3;
    const int wo0 = (tile - ho * 3) * 32;
    const int wv = t >> 6;
    const int l = t & 63;
    const int lr = l & 15;
    const int quad = l >> 4;

    const unsigned short* xTb = xT + (size_t)bb * HW * 64;

    // phase 0: stage halo region rows ho-3..ho+3, cols wo0-3..wo0+34
    static const bf16x8 zero8 = {0, 0, 0, 0, 0, 0, 0, 0};
    for (int i = t; i < RR * RC * 8; i += 256) {
        int q = i & 7;
        int rcx = i >> 3;
        int col = rcx % RC, r = rcx / RC;
        int h = ho - 3 + r, w = wo0 - 3 + col;
        bf16x8 val = zero8;
        if ((unsigned)h < (unsigned)Hh && (unsigned)w < (unsigned)Ww)
            val = *(const bf16x8*)(xTb + ((size_t)(h * Ww + w)) * 64 + q * 8);
        *(bf16x8*)&R.reg[(r * RC + col) * RS + q * 8] = val;
    }
    __syncthreads();

    // phase 1: conv 64->27 via MFMA (A from region rows 2..4, B from global)
    {
        f32x4 acc_o = {0.f, 0.f, 0.f, 0.f};
        const int mt1 = wv & 1;
        const int nt1 = wv >> 1;
#pragma unroll
        for (int k9 = 0; k9 < 9; ++k9) {
            const int di = k9 / 3, dj = k9 % 3;
            const short* ar =
                &R.reg[((di + 2) * RC + mt1 * 16 + lr + dj + 2) * RS + quad * 8];
#pragma unroll
            for (int s = 0; s < 2; ++s) {
                bf16x8 a = *(const bf16x8*)(ar + s * 32);
                bf16x8 b = *(const bf16x8*)(w27F + (((k9 * 2 + s) * 2 + nt1) << 9) + l * 8);
                acc_o = __builtin_amdgcn_mfma_f32_16x16x32_bf16(a, b, acc_o, 0, 0, 0);
            }
        }
        int ch = nt1 * 16 + lr;
        if (ch < 27) {
#pragma unroll
            for (int r = 0; r < 4; ++r)
                offm_s[ch * 33 + mt1 * 16 + quad * 4 + r] = acc_o[r];
        }
    }
    __syncthreads();

    // phase 2a: bias + 2*sigmoid
    for (int i = t; i < 27 * PT; i += 256) {
        int ch = i >> 5, pos = i & 31;
        float v = offm_s[ch * 33 + pos];
        if (ch < 18) v += ob[ch];
        else         v = 2.f / (1.f + expf(-(v + mb[ch - 18])));
        offm_s[ch * 33 + pos] = v;
    }
    __syncthreads();
    // phase 2b: bilinear params; indices region-relative (tagged global if not)
    for (int i = t; i < 9 * PT; i += 256) {
        int kk = i >> 5, pos = i & 31;
        float dy = offm_s[(2 * kk) * 33 + pos];
        float dx = offm_s[(2 * kk + 1) * 33 + pos];
        float mm = offm_s[(18 + kk) * 33 + pos];
        float py = (float)(ho - 1 + kk / 3) + dy;
        float px = (float)(wo0 + pos - 1 + kk % 3) + dx;
        float fy = floorf(py), fx = floorf(px);
        float ly = py - fy, lx = px - fx;
        int y0 = (int)fy, x0 = (int)fx;
        int y1 = y0 + 1, x1 = x0 + 1;
        float v00 = ((unsigned)y0 < (unsigned)Hh && (unsigned)x0 < (unsigned)Ww) ? 1.f : 0.f;
        float v01 = ((unsigned)y0 < (unsigned)Hh && (unsigned)x1 < (unsigned)Ww) ? 1.f : 0.f;
        float v10 = ((unsigned)y1 < (unsigned)Hh && (unsigned)x0 < (unsigned)Ww) ? 1.f : 0.f;
        float v11 = ((unsigned)y1 < (unsigned)Hh && (unsigned)x1 < (unsigned)Ww) ? 1.f : 0.f;
        s_pw[kk][0][pos] = (1.f - ly) * (1.f - lx) * mm * v00;
        s_pw[kk][1][pos] = (1.f - ly) * lx * mm * v01;
        s_pw[kk][2][pos] = ly * (1.f - lx) * mm * v10;
        s_pw[kk][3][pos] = ly * lx * mm * v11;

        auto mkidx = [&](float valid, int y, int xx) -> int {
            if (valid == 0.f) return 0;                    // weight 0: safe read
            int ry = y - (ho - 3), rx = xx - (wo0 - 3);
            if ((unsigned)ry < (unsigned)RR && (unsigned)rx < (unsigned)RC)
                return (ry * RC + rx) * RS;                // LDS element offset
            return (int)(0x80000000u | (unsigned)((y * Ww + xx) * 64));  // global
        };
        s_pi[kk][0][pos] = mkidx(v00, y0, x0);
        s_pi[kk][1][pos] = mkidx(v01, y0, x1);
        s_pi[kk][2][pos] = mkidx(v10, y1, x0);
        s_pi[kk][3][pos] = mkidx(v11, y1, x1);
    }
    __syncthreads();

    // phase 3: tap-split LDS sampling + GEMM over all 128 ocs
    const int nt = wv & 1;                   // pos half
    const int tg = wv >> 1;                  // tap group
    const int pos_l = nt * 16 + lr;
    const int cq = quad * 8;

    f32x4 acc[8];
#pragma unroll
    for (int m = 0; m < 8; ++m) acc[m] = (f32x4){0.f, 0.f, 0.f, 0.f};

    const unsigned short* wb = wTmF + l * 8;

    if (tg == 0)
        sample_gemm<0, 5>(R.reg, xTb, wb, s_pw, s_pi, pos_l, cq, acc);
    else
        sample_gemm<5, 9>(R.reg, xTb, wb, s_pw, s_pi, pos_l, cq, acc);

    __syncthreads();                          // all region/pw/pi reads done
    if (tg == 1) {
#pragma unroll
        for (int m = 0; m < 8; ++m)
            *(f32x4*)&R.mg[m * 520 + (nt * 64 + l) * 4] = acc[m];
    }
    __syncthreads();
    if (tg == 0) {
        float* outp = out + (size_t)bb * Oo * HW + tile * PT + nt * 16 + lr;
#pragma unroll
        for (int m = 0; m < 8; ++m) {
            f32x4 o = acc[m] + *(const f32x4*)&R.mg[m * 520 + (nt * 64 + l) * 4];
#pragma unroll
            for (int r = 0; r < 4; ++r) {
                int oc = m * 16 + quad * 4 + r;
                outp[(size_t)oc * HW] = o[r];
            }
        }
    }
}

extern "C" void kernel_launch(void* const* d_in, const int* in_sizes, int n_in,
                              void* d_out, int out_size, void* d_ws, size_t ws_size,
                              hipStream_t stream) {
    const float* x  = (const float*)d_in[0];
    const float* ow = (const float*)d_in[1];
    const float* ob = (const float*)d_in[2];
    const float* mw = (const float*)d_in[3];
    const float* mb = (const float*)d_in[4];
    const float* dw = (const float*)d_in[5];
    float* out = (float*)d_out;

    unsigned short* wTmF = (unsigned short*)d_ws;          // 73728 shorts
    unsigned short* w27F = wTmF + 9 * 8 * 2 * 512;         // 18432 shorts
    unsigned short* xT   = w27F + 9 * 2 * 2 * 512;         // 2359296 shorts

    hipLaunchKernelGGL(k_pre, dim3(324), dim3(256), 0, stream,
                       dw, ow, mw, x, wTmF, w27F, xT);
    hipLaunchKernelGGL(k_fused, dim3(Bc * NPB), dim3(256), 0, stream,
                       xT, ob, mb, w27F, wTmF, out);
}

// Round 3
// 106.641 us; speedup vs baseline: 1.0143x; 1.0143x over previous
//
#include <hip/hip_runtime.h>
#include <math.h>

#define Bc 4
#define Cc 64
#define Hh 96
#define Ww 96
#define Oo 128
#define HW 9216          // Hh*Ww
#define PT 32            // positions per block
#define NPB 288          // 32-pos tiles per image
#define RR 7             // region rows  (ho-3 .. ho+3)
#define RC 38            // region cols  (wo0-3 .. wo0+34)
#define RS 72            // shorts per position record (144 B: 16B-aligned, 36 banks)

typedef __attribute__((ext_vector_type(8))) short bf16x8;
typedef __attribute__((ext_vector_type(4))) float f32x4;
typedef __attribute__((ext_vector_type(4))) unsigned int u32x4;

// low/high bf16 of a packed u32 as exact f32 (1 VALU op each)
__device__ inline float bf_lo(unsigned u) {
    return __builtin_bit_cast(float, u << 16);
}
__device__ inline float bf_hi(unsigned u) {
    return __builtin_bit_cast(float, u & 0xFFFF0000u);
}
// HW RNE pack of two f32 -> 2x bf16 (src0 -> low short). Verified r2.
__device__ inline unsigned cvt_pk_bf16(float lo, float hi) {
    unsigned r;
    asm("v_cvt_pk_bf16_f32 %0, %1, %2" : "=v"(r) : "v"(lo), "v"(hi));
    return r;
}

// ---------------------------------------------------------------------------
// k_pre: (blocks 0..179) pack weights into MFMA fragment layouts, one channel
//        PAIR per thread via v_cvt_pk_bf16_f32;
//        (blocks 180..323) transpose x -> channels-last bf16 xT[b][h][w][c].
// ---------------------------------------------------------------------------
__global__ __launch_bounds__(256) void k_pre(
    const float* __restrict__ dw, const float* __restrict__ ow,
    const float* __restrict__ mw, const float* __restrict__ x,
    unsigned short* __restrict__ wTmF, unsigned short* __restrict__ w27F,
    unsigned short* __restrict__ xT)
{
    const int bid = blockIdx.x;
    const int t = threadIdx.x;
    if (bid < 180) {
        int i2 = (bid * 256 + t) * 2;            // even element index
        if (i2 < 9 * 8 * 2 * 512) {
            int j = i2 & 7;                      // even: pair (j, j+1) -> (c, c+1)
            int l = (i2 >> 3) & 63, fb = i2 >> 9;
            int s = fb & 1, m = (fb >> 1) & 7, k = fb >> 4;
            int oc = m * 16 + (l & 15);
            int c = s * 32 + (l >> 4) * 8 + j;
            float f0 = dw[(oc * 64 + c) * 9 + k];
            float f1 = dw[(oc * 64 + c + 1) * 9 + k];
            *(unsigned*)(wTmF + i2) = cvt_pk_bf16(f0, f1);
        } else {
            int jj = i2 - 9 * 8 * 2 * 512;
            if (jj < 9 * 2 * 2 * 512) {
                int j = jj & 7, l = (jj >> 3) & 63, fb2 = jj >> 9;
                int nt = fb2 & 1, s = (fb2 >> 1) & 1, k = fb2 >> 2;
                int ch = nt * 16 + (l & 15);
                int c = s * 32 + (l >> 4) * 8 + j;
                float f0 = 0.f, f1 = 0.f;
                if (ch < 18) {
                    f0 = ow[(ch * 64 + c) * 9 + k];
                    f1 = ow[(ch * 64 + c + 1) * 9 + k];
                } else if (ch < 27) {
                    f0 = mw[((ch - 18) * 64 + c) * 9 + k];
                    f1 = mw[((ch - 18) * 64 + c + 1) * 9 + k];
                }
                *(unsigned*)(w27F + jj) = cvt_pk_bf16(f0, f1);
            }
        }
    } else {
        int gp = (bid - 180) * 256 + t;          // 0..36863, one position each
        int b = gp / HW;
        int p = gp - b * HW;
        const float* xb = x + (size_t)b * Cc * HW + p;
        unsigned short* op = xT + (size_t)gp * 64;
#pragma unroll
        for (int q = 0; q < 8; ++q) {
            union { bf16x8 v8; unsigned u[4]; } u;
#pragma unroll
            for (int c = 0; c < 8; c += 2) {
                float f0 = xb[(size_t)(q * 8 + c) * HW];
                float f1 = xb[(size_t)(q * 8 + c + 1) * HW];
                u.u[c >> 1] = cvt_pk_bf16(f0, f1);   // 1 instr / 2 elements
            }
            *(bf16x8*)(op + q * 8) = u.v8;
        }
    }
}

// ---------------------------------------------------------------------------
// sample+GEMM over taps [k0,k1) (RUNTIME bounds: one loop body, small I$).
// Corners come from the LDS region (wave-uniform ballot fast path) with exact
// per-lane global fallback for tagged indices. Blend: scalar mul/fma +
// HW cvt_pk_bf16 pack (r2-verified numerics).
// ---------------------------------------------------------------------------
__device__ __forceinline__ void sample_gemm(
    const short (&reg)[RR * RC * RS],
    const unsigned short* __restrict__ xTb,
    const unsigned short* __restrict__ wb,
    const float (&pw)[9][4][PT], const int (&pi)[9][4][PT],
    int pos_l, int cq, int k0, int k1, f32x4 (&acc)[8])
{
    for (int kk = k0; kk < k1; ++kk) {
        const float w0 = pw[kk][0][pos_l], w1 = pw[kk][1][pos_l];
        const float w2 = pw[kk][2][pos_l], w3 = pw[kk][3][pos_l];
        const int i0 = pi[kk][0][pos_l], i1 = pi[kk][1][pos_l];
        const int i2 = pi[kk][2][pos_l], i3 = pi[kk][3][pos_l];
        const unsigned long long anybad = __ballot((i0 | i1 | i2 | i3) < 0);

#pragma unroll
        for (int s = 0; s < 2; ++s) {
            const int so = s * 32 + cq;
            bf16x8 c0, c1, c2, c3;
            if (anybad == 0) {                       // wave-uniform fast path
                c0 = *(const bf16x8*)(&reg[i0 + so]);
                c1 = *(const bf16x8*)(&reg[i1 + so]);
                c2 = *(const bf16x8*)(&reg[i2 + so]);
                c3 = *(const bf16x8*)(&reg[i3 + so]);
            } else {                                 // rare exact fallback
                c0 = (i0 < 0) ? *(const bf16x8*)(xTb + (i0 & 0x7FFFFFFF) + so)
                              : *(const bf16x8*)(&reg[i0 + so]);
                c1 = (i1 < 0) ? *(const bf16x8*)(xTb + (i1 & 0x7FFFFFFF) + so)
                              : *(const bf16x8*)(&reg[i1 + so]);
                c2 = (i2 < 0) ? *(const bf16x8*)(xTb + (i2 & 0x7FFFFFFF) + so)
                              : *(const bf16x8*)(&reg[i2 + so]);
                c3 = (i3 < 0) ? *(const bf16x8*)(xTb + (i3 & 0x7FFFFFFF) + so)
                              : *(const bf16x8*)(&reg[i3 + so]);
            }
            const u32x4 U0 = __builtin_bit_cast(u32x4, c0);
            const u32x4 U1 = __builtin_bit_cast(u32x4, c1);
            const u32x4 U2 = __builtin_bit_cast(u32x4, c2);
            const u32x4 U3 = __builtin_bit_cast(u32x4, c3);
            union { bf16x8 v8; unsigned u[4]; } B;
#pragma unroll
            for (int p = 0; p < 4; ++p) {            // element pair (2p, 2p+1)
                float r0 = w0 * bf_lo(U0[p]) + w1 * bf_lo(U1[p])
                         + w2 * bf_lo(U2[p]) + w3 * bf_lo(U3[p]);
                float r1 = w0 * bf_hi(U0[p]) + w1 * bf_hi(U1[p])
                         + w2 * bf_hi(U2[p]) + w3 * bf_hi(U3[p]);
                B.u[p] = cvt_pk_bf16(r0, r1);
            }
#pragma unroll
            for (int m = 0; m < 8; ++m) {
                bf16x8 A = *(const bf16x8*)(wb + (size_t)((kk * 16 + m * 2 + s) << 9));
                acc[m] = __builtin_amdgcn_mfma_f32_16x16x32_bf16(A, B.v8, acc[m], 0, 0, 0);
            }
        }
    }
}

// ---------------------------------------------------------------------------
// k_fused (512 thr / 8 waves): halo region (7x38, LDS) -> offset/mask conv
// (MFMA, waves 0-3) -> sigmoid -> bilinear params -> 4-way tap-split LDS
// sampling + MFMA GEMM -> 2-stage LDS merge tree -> store.
// ---------------------------------------------------------------------------
__global__ __launch_bounds__(512, 4) void k_fused(
    const unsigned short* __restrict__ xT, const float* __restrict__ ob,
    const float* __restrict__ mb, const unsigned short* __restrict__ w27F,
    const unsigned short* __restrict__ wTmF, float* __restrict__ out)
{
    __shared__ union RU {
        short reg[RR * RC * RS];                   // 38304 B, phases 0-3
        float mg[2][8 * 128 * 4];                  // 32768 B, merge epilogue
    } R;
    __shared__ float s_pw[9][4][PT];               // 4608 B
    __shared__ int   s_pi[9][4][PT];               // 4608 B
    __shared__ float offm_s[27 * 33];              // 3564 B

    const int t = threadIdx.x;
    const int lid = (blockIdx.x & 7) * 144 + (blockIdx.x >> 3);
    const int bb = lid / NPB;
    const int tile = lid - bb * NPB;
    const int ho = tile / 3;
    const int wo0 = (tile - ho * 3) * 32;
    const int wv = t >> 6;                         // 0..7
    const int l = t & 63;
    const int lr = l & 15;
    const int quad = l >> 4;

    const unsigned short* xTb = xT + (size_t)bb * HW * 64;

    // phase 0: stage halo region rows ho-3..ho+3, cols wo0-3..wo0+34
    static const bf16x8 zero8 = {0, 0, 0, 0, 0, 0, 0, 0};
    for (int i = t; i < RR * RC * 8; i += 512) {
        int q = i & 7;
        int rcx = i >> 3;
        int col = rcx % RC, r = rcx / RC;
        int h = ho - 3 + r, w = wo0 - 3 + col;
        bf16x8 val = zero8;
        if ((unsigned)h < (unsigned)Hh && (unsigned)w < (unsigned)Ww)
            val = *(const bf16x8*)(xTb + ((size_t)(h * Ww + w)) * 64 + q * 8);
        *(bf16x8*)&R.reg[(r * RC + col) * RS + q * 8] = val;
    }
    __syncthreads();

    // phase 1: conv 64->27 via MFMA (waves 0..3 only; 4..7 idle to barrier)
    if (wv < 4) {
        f32x4 acc_o = {0.f, 0.f, 0.f, 0.f};
        const int mt1 = wv & 1;
        const int nt1 = wv >> 1;
#pragma unroll
        for (int k9 = 0; k9 < 9; ++k9) {
            const int di = k9 / 3, dj = k9 % 3;
            const short* ar =
                &R.reg[((di + 2) * RC + mt1 * 16 + lr + dj + 2) * RS + quad * 8];
#pragma unroll
            for (int s = 0; s < 2; ++s) {
                bf16x8 a = *(const bf16x8*)(ar + s * 32);
                bf16x8 b = *(const bf16x8*)(w27F + (((k9 * 2 + s) * 2 + nt1) << 9) + l * 8);
                acc_o = __builtin_amdgcn_mfma_f32_16x16x32_bf16(a, b, acc_o, 0, 0, 0);
            }
        }
        int ch = nt1 * 16 + lr;
        if (ch < 27) {
#pragma unroll
            for (int r = 0; r < 4; ++r)
                offm_s[ch * 33 + mt1 * 16 + quad * 4 + r] = acc_o[r];
        }
    }
    __syncthreads();

    // phase 2a: bias + 2*sigmoid
    for (int i = t; i < 27 * PT; i += 512) {
        int ch = i >> 5, pos = i & 31;
        float v = offm_s[ch * 33 + pos];
        if (ch < 18) v += ob[ch];
        else         v = 2.f / (1.f + expf(-(v + mb[ch - 18])));
        offm_s[ch * 33 + pos] = v;
    }
    __syncthreads();
    // phase 2b: bilinear params; indices region-relative (tagged global if not)
    for (int i = t; i < 9 * PT; i += 512) {
        int kk = i >> 5, pos = i & 31;
        float dy = offm_s[(2 * kk) * 33 + pos];
        float dx = offm_s[(2 * kk + 1) * 33 + pos];
        float mm = offm_s[(18 + kk) * 33 + pos];
        float py = (float)(ho - 1 + kk / 3) + dy;
        float px = (float)(wo0 + pos - 1 + kk % 3) + dx;
        float fy = floorf(py), fx = floorf(px);
        float ly = py - fy, lx = px - fx;
        int y0 = (int)fy, x0 = (int)fx;
        int y1 = y0 + 1, x1 = x0 + 1;
        float v00 = ((unsigned)y0 < (unsigned)Hh && (unsigned)x0 < (unsigned)Ww) ? 1.f : 0.f;
        float v01 = ((unsigned)y0 < (unsigned)Hh && (unsigned)x1 < (unsigned)Ww) ? 1.f : 0.f;
        float v10 = ((unsigned)y1 < (unsigned)Hh && (unsigned)x0 < (unsigned)Ww) ? 1.f : 0.f;
        float v11 = ((unsigned)y1 < (unsigned)Hh && (unsigned)x1 < (unsigned)Ww) ? 1.f : 0.f;
        s_pw[kk][0][pos] = (1.f - ly) * (1.f - lx) * mm * v00;
        s_pw[kk][1][pos] = (1.f - ly) * lx * mm * v01;
        s_pw[kk][2][pos] = ly * (1.f - lx) * mm * v10;
        s_pw[kk][3][pos] = ly * lx * mm * v11;

        auto mkidx = [&](float valid, int y, int xx) -> int {
            if (valid == 0.f) return 0;                    // weight 0: safe read
            int ry = y - (ho - 3), rx = xx - (wo0 - 3);
            if ((unsigned)ry < (unsigned)RR && (unsigned)rx < (unsigned)RC)
                return (ry * RC + rx) * RS;                // LDS element offset
            return (int)(0x80000000u | (unsigned)((y * Ww + xx) * 64));  // global
        };
        s_pi[kk][0][pos] = mkidx(v00, y0, x0);
        s_pi[kk][1][pos] = mkidx(v01, y0, x1);
        s_pi[kk][2][pos] = mkidx(v10, y1, x0);
        s_pi[kk][3][pos] = mkidx(v11, y1, x1);
    }
    __syncthreads();

    // phase 3: 4-way tap-split LDS sampling + GEMM over all 128 ocs
    const int nt = wv & 1;                   // pos half
    const int tg = wv >> 1;                  // tap group 0..3
    const int pos_l = nt * 16 + lr;
    const int cq = quad * 8;
    // tap ranges: tg0 [0,3)  tg1 [3,5)  tg2 [5,7)  tg3 [7,9)
    const int k0 = (tg == 0) ? 0 : tg * 2 + 1;
    const int k1 = k0 + ((tg == 0) ? 3 : 2);

    f32x4 acc[8];
#pragma unroll
    for (int m = 0; m < 8; ++m) acc[m] = (f32x4){0.f, 0.f, 0.f, 0.f};

    const unsigned short* wb = wTmF + l * 8;

    sample_gemm(R.reg, xTb, wb, s_pw, s_pi, pos_l, cq, k0, k1, acc);

    __syncthreads();                          // all region/pw/pi reads done

    // merge stage A: tg2 -> set0, tg3 -> set1
    if (tg >= 2) {
        float* mp = &R.mg[tg - 2][(nt * 64 + l) * 4];
#pragma unroll
        for (int m = 0; m < 8; ++m)
            *(f32x4*)(mp + m * 128 * 4) = acc[m];
    }
    __syncthreads();
    if (tg < 2) {                             // tg0 += set0, tg1 += set1
        const float* mp = &R.mg[tg][(nt * 64 + l) * 4];
#pragma unroll
        for (int m = 0; m < 8; ++m)
            acc[m] += *(const f32x4*)(mp + m * 128 * 4);
    }
    __syncthreads();
    // merge stage B: tg1 -> set0
    if (tg == 1) {
        float* mp = &R.mg[0][(nt * 64 + l) * 4];
#pragma unroll
        for (int m = 0; m < 8; ++m)
            *(f32x4*)(mp + m * 128 * 4) = acc[m];
    }
    __syncthreads();
    if (tg == 0) {
        const float* mp = &R.mg[0][(nt * 64 + l) * 4];
        float* outp = out + (size_t)bb * Oo * HW + tile * PT + nt * 16 + lr;
#pragma unroll
        for (int m = 0; m < 8; ++m) {
            f32x4 o = acc[m] + *(const f32x4*)(mp + m * 128 * 4);
#pragma unroll
            for (int r = 0; r < 4; ++r) {
                int oc = m * 16 + quad * 4 + r;
                outp[(size_t)oc * HW] = o[r];
            }
        }
    }
}

extern "C" void kernel_launch(void* const* d_in, const int* in_sizes, int n_in,
                              void* d_out, int out_size, void* d_ws, size_t ws_size,
                              hipStream_t stream) {
    const float* x  = (const float*)d_in[0];
    const float* ow = (const float*)d_in[1];
    const float* ob = (const float*)d_in[2];
    const float* mw = (const float*)d_in[3];
    const float* mb = (const float*)d_in[4];
    const float* dw = (const float*)d_in[5];
    float* out = (float*)d_out;

    unsigned short* wTmF = (unsigned short*)d_ws;          // 73728 shorts
    unsigned short* w27F = wTmF + 9 * 8 * 2 * 512;         // 18432 shorts
    unsigned short* xT   = w27F + 9 * 2 * 2 * 512;         // 2359296 shorts

    hipLaunchKernelGGL(k_pre, dim3(324), dim3(256), 0, stream,
                       dw, ow, mw, x, wTmF, w27F, xT);
    hipLaunchKernelGGL(k_fused, dim3(Bc * NPB), dim3(512), 0, stream,
                       xT, ob, mb, w27F, wTmF, out);
}